// Round 9
// baseline (232.721 us; speedup 1.0000x reference)
//
#include <hip/hip_runtime.h>
#include <hip/hip_fp16.h>

#define NN 50000
#define EE 800000
#define CC 64
#define HH 2
#define LL 3
#define CAP 64     // slots per node (Poisson(16): P(>=64) ~ 1e-13)
#define NB 782     // dst buckets of 64 nodes: (50000+63)/64
#define BCAP 1280  // per-bucket capacity (mean 1023, +8 sigma)
#define CHUNK 8192 // edges per k_bin block
#define NBLK ((EE + CHUNK - 1) / CHUNK)   // 98

// R20 = R18 geometry (1 node/wave, 50k waves — R19's 2-node/wave halved TLP
// and regressed) + 8-LANE SUBGROUPS on fp16 rows. R12's 8-lane failure was
// fp32 256B rows read as strided 16B pairs; fp16 rows are 128B = 8 lanes x
// uint4 CONTIGUOUS -> one load instr gathers 8 distinct rows. Per body:
// 16 edges, 8 independent row streams (2x R18's MLP at SAME wave count),
// ~1 loop trip/node (npair~8.5, stride 8), red8 = 3 DPP levels. x converted
// to fp16 once (k_cvt) so all 3 layers share the path; FIRST epilogue
// re-reads fp32 x for the acc seed (no added seed error).

// ---------------- build (R13 verbatim) ----------------

__global__ __launch_bounds__(1024) void k_bin(const int* __restrict__ ei,
                                              int* __restrict__ bcnt,
                                              unsigned int* __restrict__ bucket) {
    __shared__ unsigned int stash[CHUNK];
    __shared__ int hist[NB];
    __shared__ int rank[NB];
    __shared__ int base[NB];

    int c0 = blockIdx.x * CHUNK;
    int n = EE - c0; if (n > CHUNK) n = CHUNK;

    for (int b = threadIdx.x; b < NB; b += 1024) { hist[b] = 0; rank[b] = 0; }
    __syncthreads();

    for (int k = threadIdx.x; k < n; k += 1024) {
        unsigned int s = (unsigned int)ei[c0 + k];
        unsigned int d = (unsigned int)ei[EE + c0 + k];
        stash[k] = (d << 16) | s;
        atomicAdd(&hist[d >> 6], 1);
    }
    __syncthreads();

    for (int b = threadIdx.x; b < NB; b += 1024) {
        int c = hist[b];
        base[b] = c ? atomicAdd(&bcnt[b], c) : 0;
    }
    __syncthreads();

    for (int k = threadIdx.x; k < n; k += 1024) {
        unsigned int pk = stash[k];
        int b = (int)(pk >> 22);
        int r = atomicAdd(&rank[b], 1);
        int pos = base[b] + r;
        if (pos < BCAP) bucket[(size_t)b * BCAP + pos] = pk;
    }
}

__global__ __launch_bounds__(256) void k_place(const unsigned int* __restrict__ bucket,
                                               const int* __restrict__ bcnt,
                                               int* __restrict__ cnt,
                                               unsigned short* __restrict__ slots) {
    __shared__ int lcnt[64];
    int b = blockIdx.x;
    if (threadIdx.x < 64) lcnt[threadIdx.x] = 0;
    __syncthreads();
    int node0 = b << 6;
    int m = bcnt[b];
    if (m > BCAP) m = BCAP;
    const unsigned int* src = bucket + (size_t)b * BCAP;
    for (int i = threadIdx.x; i < m; i += 256) {
        unsigned int pk = src[i];
        int d = (int)(pk >> 16);
        int s = (int)(pk & 0xFFFFu);
        int pos = atomicAdd(&lcnt[d - node0], 1);
        if (pos < CAP) slots[(size_t)d * CAP + pos] = (unsigned short)s;
    }
    __syncthreads();
    if (threadIdx.x < 64) {
        int node = node0 + threadIdx.x;
        if (node < NN) cnt[node] = lcnt[threadIdx.x];
    }
}

// x fp32 -> fp16 (memory-bound, ~3us); lets layer 0 share the fp16 gather path
__global__ __launch_bounds__(256) void k_cvt(const float* __restrict__ x,
                                             unsigned short* __restrict__ x16) {
    int i = blockIdx.x * 256 + threadIdx.x;          // one float4 each
    if (i >= NN * CC / 4) return;
    float4 v = ((const float4*)x)[i];
    __half2 h0 = __float22half2_rn((float2){v.x, v.y});
    __half2 h1 = __float22half2_rn((float2){v.z, v.w});
    uint2 u = {__builtin_bit_cast(unsigned, h0), __builtin_bit_cast(unsigned, h1)};
    ((uint2*)x16)[i] = u;
}

// ---------------- fused GAT layer ----------------

typedef float v2f __attribute__((ext_vector_type(2)));

template <int CTRL>
__device__ __forceinline__ float dpp_add(float v) {
    int t = __builtin_amdgcn_update_dpp(0, __float_as_int(v), CTRL, 0xF, 0xF, true);
    return v + __int_as_float(t);
}

// sum over the 8 lanes of a subgroup (8-lane aligned); all VALU-pipe DPP
__device__ __forceinline__ float red8(float v) {
    v = dpp_add<0xB1>(v);    // quad_perm [1,0,3,2] = lane^1
    v = dpp_add<0x4E>(v);    // quad_perm [2,3,0,1] = lane^2
    v = dpp_add<0x141>(v);   // row_half_mirror     = lane^4 (quads uniform)
    return v;
}

// sum across the 8 subgroups (values differ per lane)
__device__ __forceinline__ float merge8(float v) {
    v = dpp_add<0x128>(v);   // row_ror:8 = lane^8 within each 16-lane row
    v += __shfl_xor(v, 16);
    v += __shfl_xor(v, 32);
    return v;
}

// leaky_relu on a packed pair
__device__ __forceinline__ v2f lk2(v2f v) {
    v2f t = 0.2f * v;
    return __builtin_elementwise_max(v, t);
}

__device__ __forceinline__ v2f fma2(v2f a, v2f b, v2f c) {
    return __builtin_elementwise_fma(a, b, c);
}

// load a lane's 8 channels (16B fp16) of row idx; hbq pre-offset by lane octet
__device__ __forceinline__ void ldrow(const char* hbq, unsigned idx, v2f v[4]) {
    uint4 u = *(const uint4*)(hbq + ((size_t)idx << 7));
    float2 f0 = __half22float2(__builtin_bit_cast(__half2, u.x));
    float2 f1 = __half22float2(__builtin_bit_cast(__half2, u.y));
    float2 f2 = __half22float2(__builtin_bit_cast(__half2, u.z));
    float2 f3 = __half22float2(__builtin_bit_cast(__half2, u.w));
    v[0] = (v2f){f0.x, f0.y}; v[1] = (v2f){f1.x, f1.y};
    v[2] = (v2f){f2.x, f2.y}; v[3] = (v2f){f3.x, f3.y};
}

// FIRST: seeds acc = 0.25*(x + o) re-reading fp32 x. WRITE: store fp16 h_out.
template <bool FIRST, bool WRITE>
__global__ __launch_bounds__(256) void k_gat(const unsigned short* __restrict__ hin,
                                             const float* __restrict__ xf,
                                             const int* __restrict__ cnt,
                                             const unsigned short* __restrict__ slots,
                                             const float* __restrict__ att_l,
                                             const float* __restrict__ bias_l,
                                             unsigned short* __restrict__ hout,
                                             float* __restrict__ acc, int n) {
    int wid = threadIdx.x >> 6;
    int lane = threadIdx.x & 63;
    int node = blockIdx.x * 4 + wid;
    if (node >= n) return;
    int sub = lane >> 3;
    unsigned t = (unsigned)(lane & 7);               // lane owns channels [8t,8t+8)
    const char* hbq = (const char*)hin + (t << 4);
    const v2f* attv = (const v2f*)att_l;
    v2f a0[4], a1[4];
#pragma unroll
    for (int k = 0; k < 4; ++k) {
        a0[k] = attv[4 * t + k];
        a1[k] = attv[32 + 4 * t + k];
    }
    v2f hd[4];
    ldrow(hbq, (unsigned)node, hd);
    int deg = cnt[node];
    if (deg > CAP) deg = CAP;
    const unsigned* rowu = (const unsigned*)(slots + (size_t)node * CAP);

    float s0, s1;
    v2f A0[4], A1[4];

    // self-loop: all 8 subgroups, weight 1/8 (merge restores 1x) — no branch
    {
        v2f u[4];
#pragma unroll
        for (int k = 0; k < 4; ++k) u[k] = lk2(hd[k] + hd[k]);
        v2f d0 = u[0] * a0[0], d1 = u[0] * a1[0];
#pragma unroll
        for (int k = 1; k < 4; ++k) {
            d0 = fma2(u[k], a0[k], d0);
            d1 = fma2(u[k], a1[k], d1);
        }
        float p0 = red8(d0.x + d0.y);
        float p1 = red8(d1.x + d1.y);
        float e0 = 0.125f * __expf(p0), e1 = 0.125f * __expf(p1);
        s0 = e0; s1 = e1;
#pragma unroll
        for (int k = 0; k < 4; ++k) { A0[k] = e0 * hd[k]; A1[k] = e1 * hd[k]; }
    }

    // main loop: subgroup takes edge pairs (2p,2p+1); ~1 trip (npair~8.5/8).
    // One uint4 load per lane = full 128B row per 8-lane subgroup -> one load
    // instruction has 8 independent rows in flight (2x R18 MLP, same waves).
    int npair = deg >> 1;
#pragma unroll 1
    for (int p = sub; p < npair; p += 8) {
        unsigned pk = rowu[p];
        v2f va[4], vb[4];
        ldrow(hbq, pk & 0xFFFFu, va);
        ldrow(hbq, pk >> 16, vb);
        v2f ma[4], mb[4];
#pragma unroll
        for (int k = 0; k < 4; ++k) {
            ma[k] = lk2(va[k] + hd[k]);
            mb[k] = lk2(vb[k] + hd[k]);
        }
        v2f da0 = ma[0] * a0[0], da1 = ma[0] * a1[0];
        v2f db0 = mb[0] * a0[0], db1 = mb[0] * a1[0];
#pragma unroll
        for (int k = 1; k < 4; ++k) {
            da0 = fma2(ma[k], a0[k], da0); da1 = fma2(ma[k], a1[k], da1);
            db0 = fma2(mb[k], a0[k], db0); db1 = fma2(mb[k], a1[k], db1);
        }
        float pa0 = red8(da0.x + da0.y);
        float pa1 = red8(da1.x + da1.y);
        float pb0 = red8(db0.x + db0.y);
        float pb1 = red8(db1.x + db1.y);
        float ea0 = __expf(pa0), ea1 = __expf(pa1);
        float eb0 = __expf(pb0), eb1 = __expf(pb1);
        s0 += ea0 + eb0;
        s1 += ea1 + eb1;
        v2f ea0v = {ea0, ea0}, ea1v = {ea1, ea1};
        v2f eb0v = {eb0, eb0}, eb1v = {eb1, eb1};
#pragma unroll
        for (int k = 0; k < 4; ++k) {
            A0[k] = fma2(ea0v, va[k], fma2(eb0v, vb[k], A0[k]));
            A1[k] = fma2(ea1v, va[k], fma2(eb1v, vb[k], A1[k]));
        }
    }

    // tail: one odd edge, handled by one subgroup (uniform per subgroup)
    if (deg & 1) {
        int te = deg - 1;
        if (sub == ((te >> 1) & 7)) {
            unsigned s = ((const unsigned short*)rowu)[te];
            v2f hv[4];
            ldrow(hbq, s, hv);
            v2f m[4];
#pragma unroll
            for (int k = 0; k < 4; ++k) m[k] = lk2(hv[k] + hd[k]);
            v2f d0 = m[0] * a0[0], d1 = m[0] * a1[0];
#pragma unroll
            for (int k = 1; k < 4; ++k) {
                d0 = fma2(m[k], a0[k], d0);
                d1 = fma2(m[k], a1[k], d1);
            }
            float p0 = red8(d0.x + d0.y);
            float p1 = red8(d1.x + d1.y);
            float e0 = __expf(p0), e1 = __expf(p1);
            s0 += e0; s1 += e1;
            v2f e0v = {e0, e0}, e1v = {e1, e1};
#pragma unroll
            for (int k = 0; k < 4; ++k) {
                A0[k] = fma2(e0v, hv[k], A0[k]);
                A1[k] = fma2(e1v, hv[k], A1[k]);
            }
        }
    }

    // linear merge (R12-proven): merge s, normalize per-subgroup partials,
    // merge only the 8 output scalars.
    s0 = merge8(s0);
    s1 = merge8(s1);
    float inv0 = 0.5f / (s0 + 1e-16f);               // fold mean-over-heads
    float inv1 = 0.5f / (s1 + 1e-16f);
    v2f o[4];
#pragma unroll
    for (int k = 0; k < 4; ++k) {
        o[k] = inv0 * A0[k] + inv1 * A1[k];
        o[k].x = merge8(o[k].x);
        o[k].y = merge8(o[k].y);
    }

    if (sub == 0) {
        const v2f* bv = (const v2f*)bias_l;
#pragma unroll
        for (int k = 0; k < 4; ++k) o[k] += bv[4 * t + k];
        if constexpr (WRITE) {
            __half2 w0 = __float22half2_rn((float2){o[0].x, o[0].y});
            __half2 w1 = __float22half2_rn((float2){o[1].x, o[1].y});
            __half2 w2 = __float22half2_rn((float2){o[2].x, o[2].y});
            __half2 w3 = __float22half2_rn((float2){o[3].x, o[3].y});
            uint4 u = {__builtin_bit_cast(unsigned, w0),
                       __builtin_bit_cast(unsigned, w1),
                       __builtin_bit_cast(unsigned, w2),
                       __builtin_bit_cast(unsigned, w3)};
            ((uint4*)hout)[(size_t)node * 8 + t] = u;
        }
        float4* accp = (float4*)acc + (size_t)node * 16 + 2 * t;
        float4 c0, c1;
        if (FIRST) {
            // acc = 0.25*(x + h1); re-read fp32 x (coalesced, once) — no
            // fp16 error in the seed.
            const float4* xr = (const float4*)xf + (size_t)node * 16 + 2 * t;
            float4 x0 = xr[0], x1 = xr[1];
            c0.x = 0.25f * (x0.x + o[0].x); c0.y = 0.25f * (x0.y + o[0].y);
            c0.z = 0.25f * (x0.z + o[1].x); c0.w = 0.25f * (x0.w + o[1].y);
            c1.x = 0.25f * (x1.x + o[2].x); c1.y = 0.25f * (x1.y + o[2].y);
            c1.z = 0.25f * (x1.z + o[3].x); c1.w = 0.25f * (x1.w + o[3].y);
        } else {
            c0 = accp[0]; c1 = accp[1];
            c0.x += 0.25f * o[0].x; c0.y += 0.25f * o[0].y;
            c0.z += 0.25f * o[1].x; c0.w += 0.25f * o[1].y;
            c1.x += 0.25f * o[2].x; c1.y += 0.25f * o[2].y;
            c1.z += 0.25f * o[3].x; c1.w += 0.25f * o[3].y;
        }
        accp[0] = c0; accp[1] = c1;
    }
}

// ---------------- launch ----------------

static inline size_t align256(size_t x) { return (x + 255) & ~(size_t)255; }

extern "C" void kernel_launch(void* const* d_in, const int* in_sizes, int n_in,
                              void* d_out, int out_size, void* d_ws, size_t ws_size,
                              hipStream_t stream) {
    const float* x    = (const float*)d_in[0];
    const int*   ei   = (const int*)d_in[1];
    const float* att  = (const float*)d_in[2];
    const float* bias = (const float*)d_in[3];
    float* acc = (float*)d_out;   // fp32 output; feats-mean accumulated here

    char* w = (char*)d_ws;
    int* bcnt   = (int*)w;              w += align256((size_t)NB * sizeof(int));
    int* cnt    = (int*)w;              w += align256((size_t)NN * sizeof(int));
    unsigned int* bucket = (unsigned int*)w;
    w += align256((size_t)NB * BCAP * sizeof(unsigned int));
    unsigned short* slots = (unsigned short*)w;
    w += align256((size_t)NN * CAP * sizeof(unsigned short) + 256);
    unsigned short* x16 = (unsigned short*)w;
    w += align256((size_t)NN * CC * sizeof(__half));
    unsigned short* hA16 = (unsigned short*)w;
    w += align256((size_t)NN * CC * sizeof(__half));
    unsigned short* hB16 = (unsigned short*)w;
    w += align256((size_t)NN * CC * sizeof(__half));

    const int B = 256;
    const int GG = (NN + 3) / 4;   // 1 node/wave, 4 waves/block (proven TLP)

    // build (per call; ws is re-poisoned before every launch)
    k_cvt<<<(NN * CC / 4 + B - 1) / B, B, 0, stream>>>(x, x16);
    hipMemsetAsync(bcnt, 0, (size_t)NB * sizeof(int), stream);
    k_bin<<<NBLK, 1024, 0, stream>>>(ei, bcnt, bucket);
    k_place<<<NB, B, 0, stream>>>(bucket, bcnt, cnt, slots);

    // 3 fused GAT layers; all gather fp16 rows. Layer 0 seeds acc from fp32 x;
    // layer 2 skips h_out entirely (only acc is consumed).
    k_gat<true, true><<<GG, B, 0, stream>>>(
        x16, x, cnt, slots, att, bias, hA16, acc, NN);
    k_gat<false, true><<<GG, B, 0, stream>>>(
        hA16, nullptr, cnt, slots, att + (size_t)HH * CC, bias + CC, hB16, acc, NN);
    k_gat<false, false><<<GG, B, 0, stream>>>(
        hB16, nullptr, cnt, slots, att + (size_t)2 * HH * CC, bias + 2 * CC,
        nullptr, acc, NN);
}

// Round 10
// 204.140 us; speedup vs baseline: 1.1400x; 1.1400x over previous
//
#include <hip/hip_runtime.h>
#include <hip/hip_fp16.h>

#define NN 50000
#define EE 800000
#define CC 64
#define HH 2
#define LL 3
#define CAP 64     // slots per node (Poisson(16): P(>=64) ~ 1e-13)
#define NB 782     // dst buckets of 64 nodes: (50000+63)/64
#define BCAP 1280  // per-bucket capacity (mean 1023, +8 sigma)
#define CHUNK 4096 // edges per k_bin block (R21: 8192->4096, 98->196 blocks)
#define NBLK ((EE + CHUNK - 1) / CHUNK)   // 196
#define GGAT 2048  // persistent k_gat blocks: x4 waves = 8192 = 8 waves/SIMD

// R21 = R18 inner loops VERBATIM (best @193: fp16 intermediates, packed fp32,
// DPP reduce, 16-lane subgroups; R19 2-node/wave and R20 8-lane both refuted)
// + PERSISTENT k_gat blocks. R20's counters exposed a churn limit: 12500
// sub-microsecond blocks keep measured occupancy at 33-62% though VGPR allows
// 8 waves/SIMD. 2048 grid-stride blocks live the whole kernel -> residency
// reaches the cap; ~6 nodes/wave also amortizes att/bias loads. k_bin CHUNK
// halved for CU coverage (98 blocks left 60% of the machine idle).

// ---------------- build ----------------

__global__ __launch_bounds__(1024) void k_bin(const int* __restrict__ ei,
                                              int* __restrict__ bcnt,
                                              unsigned int* __restrict__ bucket) {
    __shared__ unsigned int stash[CHUNK];
    __shared__ int hist[NB];
    __shared__ int rank[NB];
    __shared__ int base[NB];

    int c0 = blockIdx.x * CHUNK;
    int n = EE - c0; if (n > CHUNK) n = CHUNK;

    for (int b = threadIdx.x; b < NB; b += 1024) { hist[b] = 0; rank[b] = 0; }
    __syncthreads();

    for (int k = threadIdx.x; k < n; k += 1024) {
        unsigned int s = (unsigned int)ei[c0 + k];
        unsigned int d = (unsigned int)ei[EE + c0 + k];
        stash[k] = (d << 16) | s;
        atomicAdd(&hist[d >> 6], 1);
    }
    __syncthreads();

    for (int b = threadIdx.x; b < NB; b += 1024) {
        int c = hist[b];
        base[b] = c ? atomicAdd(&bcnt[b], c) : 0;
    }
    __syncthreads();

    for (int k = threadIdx.x; k < n; k += 1024) {
        unsigned int pk = stash[k];
        int b = (int)(pk >> 22);
        int r = atomicAdd(&rank[b], 1);
        int pos = base[b] + r;
        if (pos < BCAP) bucket[(size_t)b * BCAP + pos] = pk;
    }
}

__global__ __launch_bounds__(256) void k_place(const unsigned int* __restrict__ bucket,
                                               const int* __restrict__ bcnt,
                                               int* __restrict__ cnt,
                                               unsigned short* __restrict__ slots) {
    __shared__ int lcnt[64];
    int b = blockIdx.x;
    if (threadIdx.x < 64) lcnt[threadIdx.x] = 0;
    __syncthreads();
    int node0 = b << 6;
    int m = bcnt[b];
    if (m > BCAP) m = BCAP;
    const unsigned int* src = bucket + (size_t)b * BCAP;
    for (int i = threadIdx.x; i < m; i += 256) {
        unsigned int pk = src[i];
        int d = (int)(pk >> 16);
        int s = (int)(pk & 0xFFFFu);
        int pos = atomicAdd(&lcnt[d - node0], 1);
        if (pos < CAP) slots[(size_t)d * CAP + pos] = (unsigned short)s;
    }
    __syncthreads();
    if (threadIdx.x < 64) {
        int node = node0 + threadIdx.x;
        if (node < NN) cnt[node] = lcnt[threadIdx.x];
    }
}

// ---------------- fused GAT layer ----------------

typedef float v2f __attribute__((ext_vector_type(2)));

template <int CTRL>
__device__ __forceinline__ float dpp_add(float v) {
    int t = __builtin_amdgcn_update_dpp(0, __float_as_int(v), CTRL, 0xF, 0xF, true);
    return v + __int_as_float(t);
}

// sum over the 16 lanes of a subgroup (subgroups are 16-lane aligned);
// fused v_add_f32_dpp on the VALU pipe — no ds_swizzle/lgkm stall (R13 win)
__device__ __forceinline__ float red16(float v) {
    v = dpp_add<0xB1>(v);    // quad_perm [1,0,3,2] = lane^1
    v = dpp_add<0x4E>(v);    // quad_perm [2,3,0,1] = lane^2
    v = dpp_add<0x141>(v);   // row_half_mirror     = lane^4 (quads uniform)
    v = dpp_add<0x140>(v);   // row_mirror          = lane^8 (halves uniform)
    return v;
}

// leaky_relu on a packed pair: pk_mul + pk_max
__device__ __forceinline__ v2f lk2(v2f v) {
    v2f t = 0.2f * v;
    return __builtin_elementwise_max(v, t);
}

__device__ __forceinline__ v2f fma2(v2f a, v2f b, v2f c) {
    return __builtin_elementwise_fma(a, b, c);
}

// load a lane's channel quad of row idx; F16 rows are 128B, fp32 rows 256B
template <bool F16>
__device__ __forceinline__ void ldrow(const char* hb, unsigned idx, unsigned q,
                                      v2f& lo, v2f& hi) {
    if constexpr (F16) {
        uint2 u = *(const uint2*)(hb + ((size_t)idx << 7) + (q << 3));
        float2 fa = __half22float2(__builtin_bit_cast(__half2, u.x));
        float2 fb = __half22float2(__builtin_bit_cast(__half2, u.y));
        lo = (v2f){fa.x, fa.y}; hi = (v2f){fb.x, fb.y};
    } else {
        float4 v = *(const float4*)(hb + ((size_t)idx << 8) + (q << 4));
        lo = (v2f){v.x, v.y}; hi = (v2f){v.z, v.w};
    }
}

// FIRST: input is fp32 x, seeds acc = 0.25*(x + o). !FIRST: input is fp16.
// WRITE: store fp16 h_out row (skipped for the last layer — only acc used).
template <bool FIRST, bool WRITE>
__global__ __launch_bounds__(256, 8) void k_gat(const void* __restrict__ hin,
                                                const int* __restrict__ cnt,
                                                const unsigned short* __restrict__ slots,
                                                const float* __restrict__ att_l,
                                                const float* __restrict__ bias_l,
                                                void* __restrict__ hout,
                                                float* __restrict__ acc, int n) {
    constexpr bool F16IN = !FIRST;
    int wid = threadIdx.x >> 6;
    int lane = threadIdx.x & 63;
    int sub = lane >> 4;
    unsigned q = (unsigned)(lane & 15);
    const char* hb = (const char*)hin;
    const v2f* attv = (const v2f*)att_l;
    v2f a0_01 = attv[2 * q],      a0_23 = attv[2 * q + 1];
    v2f a1_01 = attv[32 + 2 * q], a1_23 = attv[32 + 2 * q + 1];
    float4 b4 = ((const float4*)bias_l)[q];

    // persistent: each wave handles ~n/8192 nodes; block lives whole kernel
    for (int node = blockIdx.x * 4 + wid; node < n; node += GGAT * 4) {
        v2f hd01, hd23;
        ldrow<F16IN>(hb, (unsigned)node, q, hd01, hd23);
        int deg = cnt[node];
        if (deg > CAP) deg = CAP;
        const unsigned* rowu = (const unsigned*)(slots + (size_t)node * CAP);

        float s0, s1;
        v2f A0_01, A0_23, A1_01, A1_23;

        // self-loop: all 4 subgroups, weight 1/4 (merge restores 1x) — no branch
        {
            v2f u01 = lk2(hd01 + hd01), u23 = lk2(hd23 + hd23);
            v2f d0 = fma2(u23, a0_23, u01 * a0_01);
            v2f d1 = fma2(u23, a1_23, u01 * a1_01);
            float p0 = red16(d0.x + d0.y);
            float p1 = red16(d1.x + d1.y);
            float e0 = 0.25f * __expf(p0), e1 = 0.25f * __expf(p1);
            s0 = e0; s1 = e1;
            A0_01 = e0 * hd01; A0_23 = e0 * hd23;
            A1_01 = e1 * hd01; A1_23 = e1 * hd23;
        }

        // main loop: subgroup takes edge pairs (2p, 2p+1) — one u32 = 2 indices.
        // unroll 2: compiler batches two iterations' independent loads (R16 win).
        int npair = deg >> 1;
#pragma unroll 2
        for (int p = sub; p < npair; p += 4) {
            unsigned pk = rowu[p];
            v2f va01, va23, vb01, vb23;
            ldrow<F16IN>(hb, pk & 0xFFFFu, q, va01, va23);
            ldrow<F16IN>(hb, pk >> 16, q, vb01, vb23);
            v2f ma01 = lk2(va01 + hd01), ma23 = lk2(va23 + hd23);
            v2f mb01 = lk2(vb01 + hd01), mb23 = lk2(vb23 + hd23);
            v2f da0 = fma2(ma23, a0_23, ma01 * a0_01);
            v2f da1 = fma2(ma23, a1_23, ma01 * a1_01);
            v2f db0 = fma2(mb23, a0_23, mb01 * a0_01);
            v2f db1 = fma2(mb23, a1_23, mb01 * a1_01);
            float pa0 = red16(da0.x + da0.y);
            float pa1 = red16(da1.x + da1.y);
            float pb0 = red16(db0.x + db0.y);
            float pb1 = red16(db1.x + db1.y);
            float ea0 = __expf(pa0), ea1 = __expf(pa1);
            float eb0 = __expf(pb0), eb1 = __expf(pb1);
            s0 += ea0 + eb0;
            s1 += ea1 + eb1;
            v2f ea0v = {ea0, ea0}, ea1v = {ea1, ea1};
            v2f eb0v = {eb0, eb0}, eb1v = {eb1, eb1};
            A0_01 = fma2(ea0v, va01, fma2(eb0v, vb01, A0_01));
            A0_23 = fma2(ea0v, va23, fma2(eb0v, vb23, A0_23));
            A1_01 = fma2(ea1v, va01, fma2(eb1v, vb01, A1_01));
            A1_23 = fma2(ea1v, va23, fma2(eb1v, vb23, A1_23));
        }

        // tail: one odd edge, handled by one subgroup (uniform per subgroup)
        if (deg & 1) {
            int t = deg - 1;
            if (sub == ((t >> 1) & 3)) {
                unsigned s = ((const unsigned short*)rowu)[t];
                v2f hv01, hv23;
                ldrow<F16IN>(hb, s, q, hv01, hv23);
                v2f m01 = lk2(hv01 + hd01), m23 = lk2(hv23 + hd23);
                v2f d0 = fma2(m23, a0_23, m01 * a0_01);
                v2f d1 = fma2(m23, a1_23, m01 * a1_01);
                float p0 = red16(d0.x + d0.y);
                float p1 = red16(d1.x + d1.y);
                float e0 = __expf(p0), e1 = __expf(p1);
                s0 += e0; s1 += e1;
                v2f e0v = {e0, e0}, e1v = {e1, e1};
                A0_01 = fma2(e0v, hv01, A0_01); A0_23 = fma2(e0v, hv23, A0_23);
                A1_01 = fma2(e1v, hv01, A1_01); A1_23 = fma2(e1v, hv23, A1_23);
            }
        }

        // merge the 4 subgroups: plain sums (cross-row — DPP can't, keep shfl)
#pragma unroll
        for (int step = 16; step <= 32; step <<= 1) {
            s0 += __shfl_xor(s0, step);
            s1 += __shfl_xor(s1, step);
            A0_01.x += __shfl_xor(A0_01.x, step); A0_01.y += __shfl_xor(A0_01.y, step);
            A0_23.x += __shfl_xor(A0_23.x, step); A0_23.y += __shfl_xor(A0_23.y, step);
            A1_01.x += __shfl_xor(A1_01.x, step); A1_01.y += __shfl_xor(A1_01.y, step);
            A1_23.x += __shfl_xor(A1_23.x, step); A1_23.y += __shfl_xor(A1_23.y, step);
        }

        if (sub == 0) {
            float inv0 = 0.5f / (s0 + 1e-16f);       // fold mean-over-heads
            float inv1 = 0.5f / (s1 + 1e-16f);
            v2f o01, o23;
            o01.x = A0_01.x * inv0 + A1_01.x * inv1 + b4.x;
            o01.y = A0_01.y * inv0 + A1_01.y * inv1 + b4.y;
            o23.x = A0_23.x * inv0 + A1_23.x * inv1 + b4.z;
            o23.y = A0_23.y * inv0 + A1_23.y * inv1 + b4.w;
            if constexpr (WRITE) {
                __half2 w0 = __float22half2_rn((float2){o01.x, o01.y});
                __half2 w1 = __float22half2_rn((float2){o23.x, o23.y});
                uint2 u = {__builtin_bit_cast(unsigned, w0),
                           __builtin_bit_cast(unsigned, w1)};
                *(uint2*)((char*)hout + ((size_t)node << 7) + (q << 3)) = u;
            }
            float4* accp = (float4*)acc + (size_t)node * 16 + q;
            float4 ac;
            if (FIRST) {
                // acc = 0.25*(x + h1); hd holds x's row quad (fp32)
                ac.x = 0.25f * (hd01.x + o01.x); ac.y = 0.25f * (hd01.y + o01.y);
                ac.z = 0.25f * (hd23.x + o23.x); ac.w = 0.25f * (hd23.y + o23.y);
            } else {
                ac = *accp;
                ac.x += 0.25f * o01.x; ac.y += 0.25f * o01.y;
                ac.z += 0.25f * o23.x; ac.w += 0.25f * o23.y;
            }
            *accp = ac;
        }
    }
}

// ---------------- launch ----------------

static inline size_t align256(size_t x) { return (x + 255) & ~(size_t)255; }

extern "C" void kernel_launch(void* const* d_in, const int* in_sizes, int n_in,
                              void* d_out, int out_size, void* d_ws, size_t ws_size,
                              hipStream_t stream) {
    const float* x    = (const float*)d_in[0];
    const int*   ei   = (const int*)d_in[1];
    const float* att  = (const float*)d_in[2];
    const float* bias = (const float*)d_in[3];
    float* acc = (float*)d_out;   // fp32 output; feats-mean accumulated here

    char* w = (char*)d_ws;
    int* bcnt   = (int*)w;              w += align256((size_t)NB * sizeof(int));
    int* cnt    = (int*)w;              w += align256((size_t)NN * sizeof(int));
    unsigned int* bucket = (unsigned int*)w;
    w += align256((size_t)NB * BCAP * sizeof(unsigned int));
    unsigned short* slots = (unsigned short*)w;
    w += align256((size_t)NN * CAP * sizeof(unsigned short) + 256);
    void* hA16  = (void*)w;             w += align256((size_t)NN * CC * sizeof(__half));
    void* hB16  = (void*)w;             w += align256((size_t)NN * CC * sizeof(__half));

    const int B = 256;

    // build (per call; ws is re-poisoned before every launch)
    hipMemsetAsync(bcnt, 0, (size_t)NB * sizeof(int), stream);
    k_bin<<<NBLK, 1024, 0, stream>>>(ei, bcnt, bucket);
    k_place<<<NB, B, 0, stream>>>(bucket, bcnt, cnt, slots);

    // 3 fused GAT layers (persistent 2048-block grids); layer 0 reads fp32 x,
    // seeds acc = 0.25*(x + h1), writes fp16 h1; layers 1/2 gather fp16;
    // layer 2 skips h_out entirely.
    k_gat<true, true><<<GGAT, B, 0, stream>>>(
        x, cnt, slots, att, bias, hA16, acc, NN);
    k_gat<false, true><<<GGAT, B, 0, stream>>>(
        hA16, cnt, slots, att + (size_t)HH * CC, bias + CC, hB16, acc, NN);
    k_gat<false, false><<<GGAT, B, 0, stream>>>(
        hB16, cnt, slots, att + (size_t)2 * HH * CC, bias + 2 * CC, nullptr, acc, NN);
}

// Round 12
// 193.105 us; speedup vs baseline: 1.2052x; 1.0571x over previous
//
#include <hip/hip_runtime.h>
#include <hip/hip_fp16.h>

#define NN 50000
#define EE 800000
#define CC 64
#define HH 2
#define LL 3
#define CAP 64     // slots per node (Poisson(16): P(>=64) ~ 1e-13)
#define NB 782     // dst buckets of 64 nodes: (50000+63)/64
#define BCAP 1280  // per-bucket capacity (mean 1023, +8 sigma)
#define CHUNK 4096 // edges per k_bin block (196 blocks: covers more CUs than 98)
#define NBLK ((EE + CHUNK - 1) / CHUNK)   // 196

// R23 = R18 VERBATIM data path (best @193, passing: fp16 intermediates,
// packed fp32, DPP reduce, 16-lane subgroups, unroll-2) + two additive-only
// changes:
//  (1) slot-row L1 prefetch in k_gat: one coalesced dword load of the whole
//      128B slot row at node start, kept live by an empty asm AFTER the
//      self-loop (waitcnt lands where latency is already covered). The
//      unchanged in-loop rowu[p] loads then hit L1 (~50cy) instead of a cold
//      ~300-900cy miss on the first body. Numerics identical by construction.
//      (R22 moved the row into registers via __shfl and FAILED correctness
//      with no findable logic error — suspect bpermute-in-divergent-unrolled-
//      loop codegen; that primitive is abandoned.)
//  (2) k_bin CHUNK 8192->4096 (disjoint kernel, separately attributable):
//      196 blocks cover the machine during the bin phase; ran clean in R21.

// ---------------- build ----------------

__global__ __launch_bounds__(1024) void k_bin(const int* __restrict__ ei,
                                              int* __restrict__ bcnt,
                                              unsigned int* __restrict__ bucket) {
    __shared__ unsigned int stash[CHUNK];
    __shared__ int hist[NB];
    __shared__ int rank[NB];
    __shared__ int base[NB];

    int c0 = blockIdx.x * CHUNK;
    int n = EE - c0; if (n > CHUNK) n = CHUNK;

    for (int b = threadIdx.x; b < NB; b += 1024) { hist[b] = 0; rank[b] = 0; }
    __syncthreads();

    for (int k = threadIdx.x; k < n; k += 1024) {
        unsigned int s = (unsigned int)ei[c0 + k];
        unsigned int d = (unsigned int)ei[EE + c0 + k];
        stash[k] = (d << 16) | s;
        atomicAdd(&hist[d >> 6], 1);
    }
    __syncthreads();

    for (int b = threadIdx.x; b < NB; b += 1024) {
        int c = hist[b];
        base[b] = c ? atomicAdd(&bcnt[b], c) : 0;
    }
    __syncthreads();

    for (int k = threadIdx.x; k < n; k += 1024) {
        unsigned int pk = stash[k];
        int b = (int)(pk >> 22);
        int r = atomicAdd(&rank[b], 1);
        int pos = base[b] + r;
        if (pos < BCAP) bucket[(size_t)b * BCAP + pos] = pk;
    }
}

__global__ __launch_bounds__(256) void k_place(const unsigned int* __restrict__ bucket,
                                               const int* __restrict__ bcnt,
                                               int* __restrict__ cnt,
                                               unsigned short* __restrict__ slots) {
    __shared__ int lcnt[64];
    int b = blockIdx.x;
    if (threadIdx.x < 64) lcnt[threadIdx.x] = 0;
    __syncthreads();
    int node0 = b << 6;
    int m = bcnt[b];
    if (m > BCAP) m = BCAP;
    const unsigned int* src = bucket + (size_t)b * BCAP;
    for (int i = threadIdx.x; i < m; i += 256) {
        unsigned int pk = src[i];
        int d = (int)(pk >> 16);
        int s = (int)(pk & 0xFFFFu);
        int pos = atomicAdd(&lcnt[d - node0], 1);
        if (pos < CAP) slots[(size_t)d * CAP + pos] = (unsigned short)s;
    }
    __syncthreads();
    if (threadIdx.x < 64) {
        int node = node0 + threadIdx.x;
        if (node < NN) cnt[node] = lcnt[threadIdx.x];
    }
}

// ---------------- fused GAT layer ----------------

typedef float v2f __attribute__((ext_vector_type(2)));

template <int CTRL>
__device__ __forceinline__ float dpp_add(float v) {
    int t = __builtin_amdgcn_update_dpp(0, __float_as_int(v), CTRL, 0xF, 0xF, true);
    return v + __int_as_float(t);
}

// sum over the 16 lanes of a subgroup (subgroups are 16-lane aligned);
// fused v_add_f32_dpp on the VALU pipe — no ds_swizzle/lgkm stall (R13 win)
__device__ __forceinline__ float red16(float v) {
    v = dpp_add<0xB1>(v);    // quad_perm [1,0,3,2] = lane^1
    v = dpp_add<0x4E>(v);    // quad_perm [2,3,0,1] = lane^2
    v = dpp_add<0x141>(v);   // row_half_mirror     = lane^4 (quads uniform)
    v = dpp_add<0x140>(v);   // row_mirror          = lane^8 (halves uniform)
    return v;
}

// leaky_relu on a packed pair: pk_mul + pk_max
__device__ __forceinline__ v2f lk2(v2f v) {
    v2f t = 0.2f * v;
    return __builtin_elementwise_max(v, t);
}

__device__ __forceinline__ v2f fma2(v2f a, v2f b, v2f c) {
    return __builtin_elementwise_fma(a, b, c);
}

// load a lane's channel quad of row idx; F16 rows are 128B, fp32 rows 256B
template <bool F16>
__device__ __forceinline__ void ldrow(const char* hb, unsigned idx, unsigned q,
                                      v2f& lo, v2f& hi) {
    if constexpr (F16) {
        uint2 u = *(const uint2*)(hb + ((size_t)idx << 7) + (q << 3));
        float2 fa = __half22float2(__builtin_bit_cast(__half2, u.x));
        float2 fb = __half22float2(__builtin_bit_cast(__half2, u.y));
        lo = (v2f){fa.x, fa.y}; hi = (v2f){fb.x, fb.y};
    } else {
        float4 v = *(const float4*)(hb + ((size_t)idx << 8) + (q << 4));
        lo = (v2f){v.x, v.y}; hi = (v2f){v.z, v.w};
    }
}

// FIRST: input is fp32 x, seeds acc = 0.25*(x + o). !FIRST: input is fp16.
// WRITE: store fp16 h_out row (skipped for the last layer — only acc used).
template <bool FIRST, bool WRITE>
__global__ __launch_bounds__(256) void k_gat(const void* __restrict__ hin,
                                             const int* __restrict__ cnt,
                                             const unsigned short* __restrict__ slots,
                                             const float* __restrict__ att_l,
                                             const float* __restrict__ bias_l,
                                             void* __restrict__ hout,
                                             float* __restrict__ acc, int n) {
    constexpr bool F16IN = !FIRST;
    int wid = threadIdx.x >> 6;
    int lane = threadIdx.x & 63;
    int node = blockIdx.x * 4 + wid;
    if (node >= n) return;
    int sub = lane >> 4;
    unsigned q = (unsigned)(lane & 15);
    const char* hb = (const char*)hin;
    const v2f* attv = (const v2f*)att_l;
    v2f a0_01 = attv[2 * q],      a0_23 = attv[2 * q + 1];
    v2f a1_01 = attv[32 + 2 * q], a1_23 = attv[32 + 2 * q + 1];
    v2f hd01, hd23;
    ldrow<F16IN>(hb, (unsigned)node, q, hd01, hd23);
    int deg = cnt[node];
    const unsigned* rowu = (const unsigned*)(slots + (size_t)node * CAP);
    // L1 prefetch of the whole 128B slot row (lanes 0-31, one coalesced
    // dword). Result unused by the data path; kept live after the self-loop.
    unsigned slotpf = rowu[lane & 31];
    if (deg > CAP) deg = CAP;

    float s0, s1;
    v2f A0_01, A0_23, A1_01, A1_23;

    // self-loop: all 4 subgroups, weight 1/4 (merge restores 1x) — no branch
    {
        v2f u01 = lk2(hd01 + hd01), u23 = lk2(hd23 + hd23);
        v2f d0 = fma2(u23, a0_23, u01 * a0_01);
        v2f d1 = fma2(u23, a1_23, u01 * a1_01);
        float p0 = red16(d0.x + d0.y);
        float p1 = red16(d1.x + d1.y);
        float e0 = 0.25f * __expf(p0), e1 = 0.25f * __expf(p1);
        s0 = e0; s1 = e1;
        A0_01 = e0 * hd01; A0_23 = e0 * hd23;
        A1_01 = e1 * hd01; A1_23 = e1 * hd23;
    }

    // keep the prefetch alive (rule: ablation-via-skip DCEs upstream ops);
    // placed here so the implied waitcnt lands after ~150cy of self-loop math.
    asm volatile("" :: "v"(slotpf));

    // main loop: subgroup takes edge pairs (2p, 2p+1) — one u32 = both
    // indices; rowu[p] now L1-hits thanks to the prefetch. unroll 2:
    // compiler batches two iterations' independent loads (proven R16).
    int npair = deg >> 1;
#pragma unroll 2
    for (int p = sub; p < npair; p += 4) {
        unsigned pk = rowu[p];
        v2f va01, va23, vb01, vb23;
        ldrow<F16IN>(hb, pk & 0xFFFFu, q, va01, va23);
        ldrow<F16IN>(hb, pk >> 16, q, vb01, vb23);
        v2f ma01 = lk2(va01 + hd01), ma23 = lk2(va23 + hd23);
        v2f mb01 = lk2(vb01 + hd01), mb23 = lk2(vb23 + hd23);
        v2f da0 = fma2(ma23, a0_23, ma01 * a0_01);
        v2f da1 = fma2(ma23, a1_23, ma01 * a1_01);
        v2f db0 = fma2(mb23, a0_23, mb01 * a0_01);
        v2f db1 = fma2(mb23, a1_23, mb01 * a1_01);
        float pa0 = red16(da0.x + da0.y);
        float pa1 = red16(da1.x + da1.y);
        float pb0 = red16(db0.x + db0.y);
        float pb1 = red16(db1.x + db1.y);
        float ea0 = __expf(pa0), ea1 = __expf(pa1);
        float eb0 = __expf(pb0), eb1 = __expf(pb1);
        s0 += ea0 + eb0;
        s1 += ea1 + eb1;
        v2f ea0v = {ea0, ea0}, ea1v = {ea1, ea1};
        v2f eb0v = {eb0, eb0}, eb1v = {eb1, eb1};
        A0_01 = fma2(ea0v, va01, fma2(eb0v, vb01, A0_01));
        A0_23 = fma2(ea0v, va23, fma2(eb0v, vb23, A0_23));
        A1_01 = fma2(ea1v, va01, fma2(eb1v, vb01, A1_01));
        A1_23 = fma2(ea1v, va23, fma2(eb1v, vb23, A1_23));
    }

    // tail: one odd edge, handled by one subgroup (uniform per subgroup)
    if (deg & 1) {
        int t = deg - 1;
        if (sub == ((t >> 1) & 3)) {
            unsigned s = ((const unsigned short*)rowu)[t];
            v2f hv01, hv23;
            ldrow<F16IN>(hb, s, q, hv01, hv23);
            v2f m01 = lk2(hv01 + hd01), m23 = lk2(hv23 + hd23);
            v2f d0 = fma2(m23, a0_23, m01 * a0_01);
            v2f d1 = fma2(m23, a1_23, m01 * a1_01);
            float p0 = red16(d0.x + d0.y);
            float p1 = red16(d1.x + d1.y);
            float e0 = __expf(p0), e1 = __expf(p1);
            s0 += e0; s1 += e1;
            v2f e0v = {e0, e0}, e1v = {e1, e1};
            A0_01 = fma2(e0v, hv01, A0_01); A0_23 = fma2(e0v, hv23, A0_23);
            A1_01 = fma2(e1v, hv01, A1_01); A1_23 = fma2(e1v, hv23, A1_23);
        }
    }

    // merge the 4 subgroups: plain sums (cross-row — DPP can't, keep shfl)
#pragma unroll
    for (int step = 16; step <= 32; step <<= 1) {
        s0 += __shfl_xor(s0, step);
        s1 += __shfl_xor(s1, step);
        A0_01.x += __shfl_xor(A0_01.x, step); A0_01.y += __shfl_xor(A0_01.y, step);
        A0_23.x += __shfl_xor(A0_23.x, step); A0_23.y += __shfl_xor(A0_23.y, step);
        A1_01.x += __shfl_xor(A1_01.x, step); A1_01.y += __shfl_xor(A1_01.y, step);
        A1_23.x += __shfl_xor(A1_23.x, step); A1_23.y += __shfl_xor(A1_23.y, step);
    }

    if (sub == 0) {
        float inv0 = 0.5f / (s0 + 1e-16f);       // fold mean-over-heads
        float inv1 = 0.5f / (s1 + 1e-16f);
        float4 b4 = ((const float4*)bias_l)[q];
        v2f o01, o23;
        o01.x = A0_01.x * inv0 + A1_01.x * inv1 + b4.x;
        o01.y = A0_01.y * inv0 + A1_01.y * inv1 + b4.y;
        o23.x = A0_23.x * inv0 + A1_23.x * inv1 + b4.z;
        o23.y = A0_23.y * inv0 + A1_23.y * inv1 + b4.w;
        if constexpr (WRITE) {
            __half2 w0 = __float22half2_rn((float2){o01.x, o01.y});
            __half2 w1 = __float22half2_rn((float2){o23.x, o23.y});
            uint2 u = {__builtin_bit_cast(unsigned, w0),
                       __builtin_bit_cast(unsigned, w1)};
            *(uint2*)((char*)hout + ((size_t)node << 7) + (q << 3)) = u;
        }
        float4* accp = (float4*)acc + (size_t)node * 16 + q;
        float4 ac;
        if (FIRST) {
            // acc = 0.25*(x + h1); hd holds x's row quad (fp32)
            ac.x = 0.25f * (hd01.x + o01.x); ac.y = 0.25f * (hd01.y + o01.y);
            ac.z = 0.25f * (hd23.x + o23.x); ac.w = 0.25f * (hd23.y + o23.y);
        } else {
            ac = *accp;
            ac.x += 0.25f * o01.x; ac.y += 0.25f * o01.y;
            ac.z += 0.25f * o23.x; ac.w += 0.25f * o23.y;
        }
        *accp = ac;
    }
}

// ---------------- launch ----------------

static inline size_t align256(size_t x) { return (x + 255) & ~(size_t)255; }

extern "C" void kernel_launch(void* const* d_in, const int* in_sizes, int n_in,
                              void* d_out, int out_size, void* d_ws, size_t ws_size,
                              hipStream_t stream) {
    const float* x    = (const float*)d_in[0];
    const int*   ei   = (const int*)d_in[1];
    const float* att  = (const float*)d_in[2];
    const float* bias = (const float*)d_in[3];
    float* acc = (float*)d_out;   // fp32 output; feats-mean accumulated here

    char* w = (char*)d_ws;
    int* bcnt   = (int*)w;              w += align256((size_t)NB * sizeof(int));
    int* cnt    = (int*)w;              w += align256((size_t)NN * sizeof(int));
    unsigned int* bucket = (unsigned int*)w;
    w += align256((size_t)NB * BCAP * sizeof(unsigned int));
    unsigned short* slots = (unsigned short*)w;
    w += align256((size_t)NN * CAP * sizeof(unsigned short) + 256);
    void* hA16  = (void*)w;             w += align256((size_t)NN * CC * sizeof(__half));
    void* hB16  = (void*)w;             w += align256((size_t)NN * CC * sizeof(__half));

    const int B = 256;
    const int GG = (NN + 3) / 4;   // 1 node/wave, 4 waves/block (proven best)

    // build (per call; ws is re-poisoned before every launch)
    hipMemsetAsync(bcnt, 0, (size_t)NB * sizeof(int), stream);
    k_bin<<<NBLK, 1024, 0, stream>>>(ei, bcnt, bucket);
    k_place<<<NB, B, 0, stream>>>(bucket, bcnt, cnt, slots);

    // 3 fused GAT layers; layer 0 reads fp32 x, seeds acc = 0.25*(x + h1),
    // writes fp16 h1; layers 1/2 gather fp16; layer 2 skips h_out entirely.
    k_gat<true, true><<<GG, B, 0, stream>>>(
        x, cnt, slots, att, bias, hA16, acc, NN);
    k_gat<false, true><<<GG, B, 0, stream>>>(
        hA16, cnt, slots, att + (size_t)HH * CC, bias + CC, hB16, acc, NN);
    k_gat<false, false><<<GG, B, 0, stream>>>(
        hB16, cnt, slots, att + (size_t)2 * HH * CC, bias + 2 * CC, nullptr, acc, NN);
}